// Round 8
// baseline (423.908 us; speedup 1.0000x reference)
//
#include <hip/hip_runtime.h>
#include <stdint.h>

using bf16x8 = __attribute__((ext_vector_type(8))) short;
using f32x4  = __attribute__((ext_vector_type(4))) float;
using u32x4  = __attribute__((ext_vector_type(4))) unsigned int;
using u32x2  = __attribute__((ext_vector_type(2))) unsigned int;

#define DEVFN static __device__ __forceinline__
#define MFMA16 __builtin_amdgcn_mfma_f32_16x16x32_bf16

#define NB 16
#define NC 256
#define NQ 4096

// workspace offsets (bytes)
#define OFF_WQ   0u
#define OFF_WK   131072u
#define OFF_WV   262144u
#define OFF_WP   393216u
#define OFF_BQ   524288u
#define OFF_BK   525312u
#define OFF_BV   526336u
#define OFF_BP   527360u
#define OFF_PEW  528384u   /* [9][256] f32 */
#define OFF_PEB  537600u   /* [256] f32   */
#define OFF_QP   1048576u  /* [B][4096][256] bf16 */
#define OFF_KS   34603008u /* [B][256][256]  bf16 */
#define OFF_VT   36700160u /* [B][256(ch)][256(kv)] bf16 */
#define OFF_Y    38797312u /* [B][4096][256] bf16 */

DEVFN unsigned short f2bf(float f) {
  unsigned u = __builtin_bit_cast(unsigned, f);
  return (unsigned short)((u + 0x8000u) >> 16);
}
DEVFN float bf2f(unsigned short s) {
  return __builtin_bit_cast(float, ((unsigned)s) << 16);
}
DEVFN unsigned pk2(float a, float b) {
  return (unsigned)f2bf(a) | ((unsigned)f2bf(b) << 16);
}

union U16B { u32x4 v; unsigned u[4]; unsigned short s[8]; };

// LDS tile: rows of 32 u32x4 (256 bf16); slot index XOR-swizzled by (row&7)
DEVFN bf16x8 ldsfrag(const u32x4* xs, int row, int kb) {
  return __builtin_bit_cast(bf16x8, xs[row * 32 + (kb ^ (row & 7))]);
}
DEVFN bf16x8 gfrag(const u32x4* w, int row, int kb) {
  return __builtin_bit_cast(bf16x8, w[row * 32 + kb]);
}

// ---------------- prep: fold BN into weights ----------------
__global__ void prep_kernel(const float* __restrict__ wq, const float* __restrict__ wqbn,
                            const float* __restrict__ wk, const float* __restrict__ wkbn,
                            const float* __restrict__ wv, const float* __restrict__ wvbn,
                            const float* __restrict__ wp, const float* __restrict__ wpbn,
                            const float* __restrict__ pe, const float* __restrict__ pebn,
                            unsigned char* __restrict__ ws) {
  const int bid = blockIdx.x, c = threadIdx.x;
  if (bid < 1024) {
    const int mat = bid >> 8, o = bid & 255;
    const float* w; const float* bn; unsigned short* wd; float* bd;
    if (mat == 0)      { w = wq; bn = wqbn; wd = (unsigned short*)(ws + OFF_WQ); bd = (float*)(ws + OFF_BQ); }
    else if (mat == 1) { w = wk; bn = wkbn; wd = (unsigned short*)(ws + OFF_WK); bd = (float*)(ws + OFF_BK); }
    else if (mat == 2) { w = wv; bn = wvbn; wd = (unsigned short*)(ws + OFF_WV); bd = (float*)(ws + OFF_BV); }
    else               { w = wp; bn = wpbn; wd = (unsigned short*)(ws + OFF_WP); bd = (float*)(ws + OFF_BP); }
    const float s = bn[o] / sqrtf(bn[768 + o] + 1e-5f);
    wd[o * 256 + c] = f2bf(w[o * 256 + c] * s);
    if (c == 0) bd[o] = bn[256 + o] - bn[512 + o] * s;
  } else {
    const float s = pebn[c] / sqrtf(pebn[768 + c] + 1e-5f);
    float* pw = (float*)(ws + OFF_PEW);
    #pragma unroll
    for (int kk = 0; kk < 9; ++kk) pw[kk * 256 + c] = pe[c * 9 + kk] * s;
    ((float*)(ws + OFF_PEB))[c] = pebn[256 + c] - pebn[512 + c] * s;
  }
}

// ---------------- q projection ----------------
__global__ __launch_bounds__(512) void qproj_kernel(const float* __restrict__ q,
                                                    unsigned char* __restrict__ ws) {
  __shared__ u32x4 xs[4096];
  const int b = blockIdx.x >> 5, ntile = blockIdx.x & 31;
  const int t = threadIdx.x;
  {
    const int n4 = t & 31, cg = t >> 5;   // 4 rows, 16 channels per thread
    const float* qb = q + (size_t)b * NC * NQ + ntile * 128 + n4 * 4;
    f32x4 f4[16];
    #pragma unroll
    for (int cc = 0; cc < 16; ++cc)
      f4[cc] = *(const f32x4*)(qb + (size_t)(cg * 16 + cc) * NQ);
    #pragma unroll
    for (int rr = 0; rr < 4; ++rr) {
      const int row = n4 * 4 + rr;
      #pragma unroll
      for (int s = 0; s < 2; ++s) {
        U16B pk;
        #pragma unroll
        for (int j = 0; j < 8; ++j) pk.s[j] = f2bf(f4[s * 8 + j][rr]);
        xs[row * 32 + ((cg * 2 + s) ^ (row & 7))] = pk.v;
      }
    }
  }
  __syncthreads();
  const int l = t & 63, w = t >> 6;
  const int lm = l & 15, lg = l >> 4;
  const int nsub = (w & 1) * 64, osub = (w >> 1) * 64;
  const u32x4* wm = (const u32x4*)(ws + OFF_WQ);
  const f32x4 fz = {0.f, 0.f, 0.f, 0.f};
  f32x4 acc[4][4];   // [o-tile][n-tile]: D row = o, col = n
  #pragma unroll
  for (int i = 0; i < 4; ++i)
    #pragma unroll
    for (int j = 0; j < 4; ++j) acc[i][j] = fz;
  for (int c0 = 0; c0 < 256; c0 += 32) {
    const int kb = (c0 >> 3) + lg;
    bf16x8 af[4], bfv[4];
    #pragma unroll
    for (int i = 0; i < 4; ++i) af[i] = gfrag(wm, osub + i * 16 + lm, kb);
    #pragma unroll
    for (int j = 0; j < 4; ++j) bfv[j] = ldsfrag(xs, nsub + j * 16 + lm, kb);
    #pragma unroll
    for (int i = 0; i < 4; ++i)
      #pragma unroll
      for (int j = 0; j < 4; ++j) acc[i][j] = MFMA16(af[i], bfv[j], acc[i][j], 0, 0, 0);
  }
  const float* bias = (const float*)(ws + OFF_BQ);
  unsigned short* qp = (unsigned short*)(ws + OFF_QP) + ((size_t)b * NQ + ntile * 128) * NC;
  #pragma unroll
  for (int i = 0; i < 4; ++i) {
    const int ob = osub + i * 16 + lg * 4;
    const f32x4 b4 = *(const f32x4*)(bias + ob);
    #pragma unroll
    for (int j = 0; j < 4; ++j) {
      const int n = nsub + j * 16 + lm;
      u32x2 pv = { pk2(acc[i][j][0] + b4[0], acc[i][j][1] + b4[1]),
                   pk2(acc[i][j][2] + b4[2], acc[i][j][3] + b4[3]) };
      *(u32x2*)(qp + (size_t)n * NC + ob) = pv;
    }
  }
}

// ---------------- pooled K/V projection ----------------
// 8 waves: osub = (w>>1)*64 (0..192), kvsub = (w&1)*16  [BUGFIX: was osub = w*64 -> OOB]
__global__ __launch_bounds__(512) void kvproj_kernel(const float* __restrict__ kin,
                                                     const float* __restrict__ vin,
                                                     unsigned char* __restrict__ ws) {
  __shared__ u32x4 xs[1024];  // 32 rows x 256 ch bf16, swizzled
  const int bid = blockIdx.x;
  const int b = bid >> 4, which = (bid >> 3) & 1, part = bid & 7;
  const int t = threadIdx.x;
  {
    const int nl = t & 31, cq = t >> 5;  // row, 16 ch per thread
    const int kv = part * 32 + nl;
    const int yy = kv >> 4, xx = kv & 15;
    const float* src = (which ? vin : kin) + (size_t)b * NC * 1024 + (2 * yy) * 32 + 2 * xx;
    #pragma unroll
    for (int s = 0; s < 2; ++s) {
      const int c0 = cq * 16 + s * 8;
      U16B pk;
      #pragma unroll
      for (int j = 0; j < 8; ++j) {
        const float* p = src + (size_t)(c0 + j) * 1024;
        const float2 p01 = *(const float2*)p;
        const float2 p23 = *(const float2*)(p + 32);
        pk.s[j] = f2bf((p01.x + p01.y + p23.x + p23.y) * 0.25f);
      }
      xs[nl * 32 + ((c0 >> 3) ^ (nl & 7))] = pk.v;
    }
  }
  __syncthreads();
  const int l = t & 63, w = t >> 6;
  const int lm = l & 15, lg = l >> 4;
  const int osub = (w >> 1) * 64;     // 0..192
  const int kvsub = (w & 1) * 16;     // 0 or 16
  const f32x4 fz = {0.f, 0.f, 0.f, 0.f};
  if (which == 0) {
    // K: D row = o, col = kv.  A=W rows o, B=xs rows kv
    const u32x4* wm = (const u32x4*)(ws + OFF_WK);
    f32x4 acc[4];
    #pragma unroll
    for (int i = 0; i < 4; ++i) acc[i] = fz;
    for (int c0 = 0; c0 < 256; c0 += 32) {
      const int kb = (c0 >> 3) + lg;
      bf16x8 bfv = ldsfrag(xs, kvsub + lm, kb);
      #pragma unroll
      for (int i = 0; i < 4; ++i) {
        bf16x8 af = gfrag(wm, osub + i * 16 + lm, kb);
        acc[i] = MFMA16(af, bfv, acc[i], 0, 0, 0);
      }
    }
    const float* bias = (const float*)(ws + OFF_BK);
    unsigned short* ksd = (unsigned short*)(ws + OFF_KS) + (size_t)b * 256 * NC;
    const int kv = part * 32 + kvsub + lm;
    #pragma unroll
    for (int i = 0; i < 4; ++i) {
      const int ob = osub + i * 16 + lg * 4;
      const f32x4 b4 = *(const f32x4*)(bias + ob);
      u32x2 pv = { pk2(acc[i][0] + b4[0], acc[i][1] + b4[1]),
                   pk2(acc[i][2] + b4[2], acc[i][3] + b4[3]) };
      *(u32x2*)(ksd + (size_t)kv * NC + ob) = pv;
    }
  } else {
    // V: D row = kv, col = o.  A=xs rows kv, B=W rows o  -> write V^T packed along kv
    const u32x4* wm = (const u32x4*)(ws + OFF_WV);
    f32x4 acc[4];
    #pragma unroll
    for (int j = 0; j < 4; ++j) acc[j] = fz;
    for (int c0 = 0; c0 < 256; c0 += 32) {
      const int kb = (c0 >> 3) + lg;
      bf16x8 af = ldsfrag(xs, kvsub + lm, kb);
      #pragma unroll
      for (int j = 0; j < 4; ++j) {
        bf16x8 bfv = gfrag(wm, osub + j * 16 + lm, kb);
        acc[j] = MFMA16(af, bfv, acc[j], 0, 0, 0);
      }
    }
    const float* bias = (const float*)(ws + OFF_BV);
    unsigned short* vtd = (unsigned short*)(ws + OFF_VT) + (size_t)b * 256 * 256;
    const int kvb = part * 32 + kvsub + lg * 4;
    #pragma unroll
    for (int j = 0; j < 4; ++j) {
      const int o = osub + j * 16 + lm;
      const float bo = bias[o];
      u32x2 pv = { pk2(acc[j][0] + bo, acc[j][1] + bo),
                   pk2(acc[j][2] + bo, acc[j][3] + bo) };
      *(u32x2*)(vtd + (size_t)o * 256 + kvb) = pv;
    }
  }
}

// ---------------- attention (verified round-1 16x16 version) ----------------
__global__ __launch_bounds__(256) void attn_kernel(unsigned char* __restrict__ ws) {
  __shared__ u32x4 plds[2048];     // 4 waves x [16 q][256 kv] bf16, swizzled
  __shared__ float sums[4][16];
  const int bid = blockIdx.x;
  const int qt = bid & 63, h = (bid >> 6) & 3, b = bid >> 8;
  const int t = threadIdx.x, w = t >> 6, l = t & 63;
  const int lm = l & 15, lg = l >> 4;
  const int q0 = qt * 64 + w * 16;
  const u32x4* qp = (const u32x4*)(ws + OFF_QP) + (size_t)b * NQ * 32;
  const u32x4* ksp = (const u32x4*)(ws + OFF_KS) + (size_t)b * 256 * 32;
  const u32x4* vtp = (const u32x4*)(ws + OFF_VT) + (size_t)(b * 4 + h) * 64 * 32;

  bf16x8 qf[2];
  #pragma unroll
  for (int kk = 0; kk < 2; ++kk)
    qf[kk] = __builtin_bit_cast(bf16x8, qp[(q0 + lm) * 32 + h * 8 + kk * 4 + lg]);

  const f32x4 fz = {0.f, 0.f, 0.f, 0.f};
  f32x4 st[16];
  #pragma unroll
  for (int tk = 0; tk < 16; ++tk) st[tk] = fz;
  #pragma unroll
  for (int tk = 0; tk < 16; ++tk) {
    #pragma unroll
    for (int kk = 0; kk < 2; ++kk) {
      bf16x8 kf = __builtin_bit_cast(bf16x8, ksp[(tk * 16 + lm) * 32 + h * 8 + kk * 4 + lg]);
      st[tk] = MFMA16(kf, qf[kk], st[tk], 0, 0, 0);   // S^T[kv][q]
    }
  }
  // softmax over kv for this lane's q-row (lane holds kv = 16*tk + 4*lg + r)
  float mx = -3.0e38f;
  #pragma unroll
  for (int tk = 0; tk < 16; ++tk)
    #pragma unroll
    for (int r = 0; r < 4; ++r) mx = fmaxf(mx, st[tk][r]);
  mx = fmaxf(mx, __shfl_xor(mx, 16));
  mx = fmaxf(mx, __shfl_xor(mx, 32));
  float sum = 0.f;
  #pragma unroll
  for (int tk = 0; tk < 16; ++tk)
    #pragma unroll
    for (int r = 0; r < 4; ++r) {
      const float e = __expf(0.125f * (st[tk][r] - mx));
      st[tk][r] = e; sum += e;
    }
  sum += __shfl_xor(sum, 16);
  sum += __shfl_xor(sum, 32);
  if (l < 16) sums[w][l] = sum;
  // pack P to LDS: row = q(lm), 4 consecutive kv per tile
  u32x2* pw = (u32x2*)(plds + w * 512);
  #pragma unroll
  for (int tk = 0; tk < 16; ++tk) {
    const int slot = (2 * tk + (lg >> 1)) ^ (lm & 7);
    u32x2 pv = { pk2(st[tk][0], st[tk][1]), pk2(st[tk][2], st[tk][3]) };
    pw[lm * 64 + slot * 2 + (lg & 1)] = pv;
  }
  __syncthreads();
  // PV
  f32x4 yacc[4];
  #pragma unroll
  for (int jj = 0; jj < 4; ++jj) yacc[jj] = fz;
  const u32x4* pr = plds + w * 512;
  for (int kk = 0; kk < 8; ++kk) {
    bf16x8 pf = __builtin_bit_cast(bf16x8, pr[lm * 32 + ((kk * 4 + lg) ^ (lm & 7))]);
    #pragma unroll
    for (int jj = 0; jj < 4; ++jj) {
      bf16x8 vf = __builtin_bit_cast(bf16x8, vtp[(jj * 16 + lm) * 32 + kk * 4 + lg]);
      yacc[jj] = MFMA16(pf, vf, yacc[jj], 0, 0, 0);
    }
  }
  unsigned short* yo = (unsigned short*)(ws + OFF_Y) + (size_t)b * NQ * NC;
  #pragma unroll
  for (int r = 0; r < 4; ++r) {
    const float inv = __builtin_amdgcn_rcpf(sums[w][lg * 4 + r]);
    const size_t rowoff = (size_t)(q0 + lg * 4 + r) * NC + h * 64;
    #pragma unroll
    for (int jj = 0; jj < 4; ++jj)
      yo[rowoff + jj * 16 + lm] = f2bf(yacc[jj][r] * inv);
  }
}

// ---------------- dwconv + add + proj ----------------
__global__ __launch_bounds__(512) void final_kernel(float* __restrict__ out,
                                                    unsigned char* __restrict__ ws) {
  __shared__ u32x4 xs[4096];
  const int b = blockIdx.x >> 5, ntile = blockIdx.x & 31;
  const int t = threadIdx.x;
  {
    const int nl = t & 127, cq = t >> 7;
    const int n = ntile * 128 + nl;
    const int yy = n >> 6, xx = n & 63;
    const u32x4* qp = (const u32x4*)(ws + OFF_QP) + (size_t)b * NQ * 32;
    const u32x4* yv = (const u32x4*)(ws + OFF_Y) + (size_t)b * NQ * 32;
    const float* pew = (const float*)(ws + OFF_PEW);
    const float* peb = (const float*)(ws + OFF_PEB);
    #pragma unroll
    for (int it = 0; it < 8; ++it) {
      const int c0 = cq * 8 + it * 32, cb = c0 >> 3;
      float a8[8];
      #pragma unroll
      for (int j = 0; j < 8; ++j) a8[j] = peb[c0 + j];
      #pragma unroll
      for (int dy = -1; dy <= 1; ++dy) {
        #pragma unroll
        for (int dx = -1; dx <= 1; ++dx) {
          const int y2 = yy + dy, x2 = xx + dx;
          if (y2 >= 0 && y2 < 64 && x2 >= 0 && x2 < 64) {
            U16B qv; qv.v = qp[(size_t)(y2 * 64 + x2) * 32 + cb];
            const float* wr = pew + ((dy + 1) * 3 + (dx + 1)) * 256 + c0;
            #pragma unroll
            for (int j = 0; j < 8; ++j) a8[j] += bf2f(qv.s[j]) * wr[j];
          }
        }
      }
      U16B yvv; yvv.v = yv[(size_t)n * 32 + cb];
      U16B pk;
      #pragma unroll
      for (int j = 0; j < 8; ++j) pk.s[j] = f2bf(a8[j] + bf2f(yvv.s[j]));
      xs[nl * 32 + (cb ^ (nl & 7))] = pk.v;
    }
  }
  __syncthreads();
  const int l = t & 63, w = t >> 6;
  const int lm = l & 15, lg = l >> 4;
  const int osub = (w >> 1) * 64, nsub = (w & 1) * 64;
  const u32x4* wm = (const u32x4*)(ws + OFF_WP);
  const f32x4 fz = {0.f, 0.f, 0.f, 0.f};
  f32x4 acc[4][4];   // [n-tile][o-tile]: D row = n, col = o
  #pragma unroll
  for (int i = 0; i < 4; ++i)
    #pragma unroll
    for (int j = 0; j < 4; ++j) acc[i][j] = fz;
  for (int c0 = 0; c0 < 256; c0 += 32) {
    const int kb = (c0 >> 3) + lg;
    bf16x8 af[4], bfv[4];
    #pragma unroll
    for (int i = 0; i < 4; ++i) af[i] = ldsfrag(xs, nsub + i * 16 + lm, kb);
    #pragma unroll
    for (int j = 0; j < 4; ++j) bfv[j] = gfrag(wm, osub + j * 16 + lm, kb);
    #pragma unroll
    for (int i = 0; i < 4; ++i)
      #pragma unroll
      for (int j = 0; j < 4; ++j) acc[i][j] = MFMA16(af[i], bfv[j], acc[i][j], 0, 0, 0);
  }
  const float* bias = (const float*)(ws + OFF_BP);
  float* ob = out + (size_t)b * NC * NQ + ntile * 128;
  #pragma unroll
  for (int j = 0; j < 4; ++j) {
    const int o = osub + j * 16 + lm;
    const float bo = bias[o];
    #pragma unroll
    for (int i = 0; i < 4; ++i) {
      const int nb = nsub + i * 16 + lg * 4;
      f32x4 v = { acc[i][j][0] + bo, acc[i][j][1] + bo, acc[i][j][2] + bo, acc[i][j][3] + bo };
      *(f32x4*)(ob + (size_t)o * NQ + nb) = v;
    }
  }
}

extern "C" void kernel_launch(void* const* d_in, const int* in_sizes, int n_in,
                              void* d_out, int out_size, void* d_ws, size_t ws_size,
                              hipStream_t stream) {
  const float* q    = (const float*)d_in[0];
  const float* k    = (const float*)d_in[1];
  const float* v    = (const float*)d_in[2];
  const float* wq   = (const float*)d_in[3];
  const float* wqbn = (const float*)d_in[4];
  const float* wk   = (const float*)d_in[5];
  const float* wkbn = (const float*)d_in[6];
  const float* wv   = (const float*)d_in[7];
  const float* wvbn = (const float*)d_in[8];
  const float* pe   = (const float*)d_in[9];
  const float* pebn = (const float*)d_in[10];
  const float* wp   = (const float*)d_in[11];
  const float* wpbn = (const float*)d_in[12];
  unsigned char* ws = (unsigned char*)d_ws;

  prep_kernel<<<1025, 256, 0, stream>>>(wq, wqbn, wk, wkbn, wv, wvbn, wp, wpbn, pe, pebn, ws);
  qproj_kernel<<<512, 512, 0, stream>>>(q, ws);
  kvproj_kernel<<<256, 512, 0, stream>>>(k, v, ws);
  attn_kernel<<<4096, 256, 0, stream>>>(ws);
  final_kernel<<<512, 512, 0, stream>>>((float*)d_out, ws);
}

// Round 9
// 373.471 us; speedup vs baseline: 1.1350x; 1.1350x over previous
//
#include <hip/hip_runtime.h>
#include <stdint.h>

using bf16x8 = __attribute__((ext_vector_type(8))) short;
using f32x4  = __attribute__((ext_vector_type(4))) float;
using f32x16 = __attribute__((ext_vector_type(16))) float;
using u32x4  = __attribute__((ext_vector_type(4))) unsigned int;
using u32x2  = __attribute__((ext_vector_type(2))) unsigned int;

#define DEVFN static __device__ __forceinline__
#define MFMA16 __builtin_amdgcn_mfma_f32_16x16x32_bf16
#define MFMA32 __builtin_amdgcn_mfma_f32_32x32x16_bf16

#define NB 16
#define NC 256
#define NQ 4096

// workspace offsets (bytes)
#define OFF_WQ   0u
#define OFF_WK   131072u
#define OFF_WV   262144u
#define OFF_WP   393216u
#define OFF_BQ   524288u
#define OFF_BK   525312u
#define OFF_BV   526336u
#define OFF_BP   527360u
#define OFF_PEW  528384u   /* [9][256] f32 */
#define OFF_PEB  537600u   /* [256] f32   */
#define OFF_QP   1048576u  /* [B][4096][256] bf16 */
#define OFF_KS   34603008u /* [B][256][256]  bf16 */
#define OFF_VT   36700160u /* [B][256(ch)][256(kv, pi-permuted)] bf16 */
#define OFF_Y    38797312u /* [B][4096][256] bf16 */

DEVFN unsigned short f2bf(float f) {
  unsigned u = __builtin_bit_cast(unsigned, f);
  return (unsigned short)((u + 0x8000u) >> 16);
}
DEVFN float bf2f(unsigned short s) {
  return __builtin_bit_cast(float, ((unsigned)s) << 16);
}
DEVFN unsigned pk2(float a, float b) {
  return (unsigned)f2bf(a) | ((unsigned)f2bf(b) << 16);
}

union U16B { u32x4 v; unsigned u[4]; unsigned short s[8]; };

// LDS tile: rows of 32 u32x4 (256 bf16); slot index XOR-swizzled by (row&7)
DEVFN bf16x8 ldsfrag(const u32x4* xs, int row, int kb) {
  return __builtin_bit_cast(bf16x8, xs[row * 32 + (kb ^ (row & 7))]);
}
DEVFN bf16x8 gfrag(const u32x4* w, int row, int kb) {
  return __builtin_bit_cast(bf16x8, w[row * 32 + kb]);
}

// ---------------- prep: fold BN into weights ----------------
__global__ void prep_kernel(const float* __restrict__ wq, const float* __restrict__ wqbn,
                            const float* __restrict__ wk, const float* __restrict__ wkbn,
                            const float* __restrict__ wv, const float* __restrict__ wvbn,
                            const float* __restrict__ wp, const float* __restrict__ wpbn,
                            const float* __restrict__ pe, const float* __restrict__ pebn,
                            unsigned char* __restrict__ ws) {
  const int bid = blockIdx.x, c = threadIdx.x;
  if (bid < 1024) {
    const int mat = bid >> 8, o = bid & 255;
    const float* w; const float* bn; unsigned short* wd; float* bd;
    if (mat == 0)      { w = wq; bn = wqbn; wd = (unsigned short*)(ws + OFF_WQ); bd = (float*)(ws + OFF_BQ); }
    else if (mat == 1) { w = wk; bn = wkbn; wd = (unsigned short*)(ws + OFF_WK); bd = (float*)(ws + OFF_BK); }
    else if (mat == 2) { w = wv; bn = wvbn; wd = (unsigned short*)(ws + OFF_WV); bd = (float*)(ws + OFF_BV); }
    else               { w = wp; bn = wpbn; wd = (unsigned short*)(ws + OFF_WP); bd = (float*)(ws + OFF_BP); }
    const float s = bn[o] / sqrtf(bn[768 + o] + 1e-5f);
    wd[o * 256 + c] = f2bf(w[o * 256 + c] * s);
    if (c == 0) bd[o] = bn[256 + o] - bn[512 + o] * s;
  } else {
    const float s = pebn[c] / sqrtf(pebn[768 + c] + 1e-5f);
    float* pw = (float*)(ws + OFF_PEW);
    #pragma unroll
    for (int kk = 0; kk < 9; ++kk) pw[kk * 256 + c] = pe[c * 9 + kk] * s;
    ((float*)(ws + OFF_PEB))[c] = pebn[256 + c] - pebn[512 + c] * s;
  }
}

// ---------------- q projection ----------------
__global__ __launch_bounds__(512) void qproj_kernel(const float* __restrict__ q,
                                                    unsigned char* __restrict__ ws) {
  __shared__ u32x4 xs[4096];
  const int b = blockIdx.x >> 5, ntile = blockIdx.x & 31;
  const int t = threadIdx.x;
  {
    const int n4 = t & 31, cg = t >> 5;   // 4 rows, 16 channels per thread
    const float* qb = q + (size_t)b * NC * NQ + ntile * 128 + n4 * 4;
    f32x4 f4[16];
    #pragma unroll
    for (int cc = 0; cc < 16; ++cc)
      f4[cc] = *(const f32x4*)(qb + (size_t)(cg * 16 + cc) * NQ);
    #pragma unroll
    for (int rr = 0; rr < 4; ++rr) {
      const int row = n4 * 4 + rr;
      #pragma unroll
      for (int s = 0; s < 2; ++s) {
        U16B pk;
        #pragma unroll
        for (int j = 0; j < 8; ++j) pk.s[j] = f2bf(f4[s * 8 + j][rr]);
        xs[row * 32 + ((cg * 2 + s) ^ (row & 7))] = pk.v;
      }
    }
  }
  __syncthreads();
  const int l = t & 63, w = t >> 6;
  const int lm = l & 15, lg = l >> 4;
  const int nsub = (w & 1) * 64, osub = (w >> 1) * 64;
  const u32x4* wm = (const u32x4*)(ws + OFF_WQ);
  const f32x4 fz = {0.f, 0.f, 0.f, 0.f};
  f32x4 acc[4][4];   // [o-tile][n-tile]: D row = o, col = n
  #pragma unroll
  for (int i = 0; i < 4; ++i)
    #pragma unroll
    for (int j = 0; j < 4; ++j) acc[i][j] = fz;
  for (int c0 = 0; c0 < 256; c0 += 32) {
    const int kb = (c0 >> 3) + lg;
    bf16x8 af[4], bfv[4];
    #pragma unroll
    for (int i = 0; i < 4; ++i) af[i] = gfrag(wm, osub + i * 16 + lm, kb);
    #pragma unroll
    for (int j = 0; j < 4; ++j) bfv[j] = ldsfrag(xs, nsub + j * 16 + lm, kb);
    #pragma unroll
    for (int i = 0; i < 4; ++i)
      #pragma unroll
      for (int j = 0; j < 4; ++j) acc[i][j] = MFMA16(af[i], bfv[j], acc[i][j], 0, 0, 0);
  }
  const float* bias = (const float*)(ws + OFF_BQ);
  unsigned short* qp = (unsigned short*)(ws + OFF_QP) + ((size_t)b * NQ + ntile * 128) * NC;
  #pragma unroll
  for (int i = 0; i < 4; ++i) {
    const int ob = osub + i * 16 + lg * 4;
    const f32x4 b4 = *(const f32x4*)(bias + ob);
    #pragma unroll
    for (int j = 0; j < 4; ++j) {
      const int n = nsub + j * 16 + lm;
      u32x2 pv = { pk2(acc[i][j][0] + b4[0], acc[i][j][1] + b4[1]),
                   pk2(acc[i][j][2] + b4[2], acc[i][j][3] + b4[3]) };
      *(u32x2*)(qp + (size_t)n * NC + ob) = pv;
    }
  }
}

// ---------------- pooled K/V projection ----------------
// 8 waves: osub = (w>>1)*64 (0..192), kvsub = (w&1)*16
// V^T is stored with each 16-kv block's 4-groups permuted g->g' (swap groups 1,2)
// so attn's linear reads deliver k-slots in the lane-local pi order.
__global__ __launch_bounds__(512) void kvproj_kernel(const float* __restrict__ kin,
                                                     const float* __restrict__ vin,
                                                     unsigned char* __restrict__ ws) {
  __shared__ u32x4 xs[1024];  // 32 rows x 256 ch bf16, swizzled
  const int bid = blockIdx.x;
  const int b = bid >> 4, which = (bid >> 3) & 1, part = bid & 7;
  const int t = threadIdx.x;
  {
    const int nl = t & 31, cq = t >> 5;  // row, 16 ch per thread
    const int kv = part * 32 + nl;
    const int yy = kv >> 4, xx = kv & 15;
    const float* src = (which ? vin : kin) + (size_t)b * NC * 1024 + (2 * yy) * 32 + 2 * xx;
    #pragma unroll
    for (int s = 0; s < 2; ++s) {
      const int c0 = cq * 16 + s * 8;
      U16B pk;
      #pragma unroll
      for (int j = 0; j < 8; ++j) {
        const float* p = src + (size_t)(c0 + j) * 1024;
        const float2 p01 = *(const float2*)p;
        const float2 p23 = *(const float2*)(p + 32);
        pk.s[j] = f2bf((p01.x + p01.y + p23.x + p23.y) * 0.25f);
      }
      xs[nl * 32 + ((c0 >> 3) ^ (nl & 7))] = pk.v;
    }
  }
  __syncthreads();
  const int l = t & 63, w = t >> 6;
  const int lm = l & 15, lg = l >> 4;
  const int osub = (w >> 1) * 64;     // 0..192
  const int kvsub = (w & 1) * 16;     // 0 or 16
  const f32x4 fz = {0.f, 0.f, 0.f, 0.f};
  if (which == 0) {
    // K: D row = o, col = kv.  A=W rows o, B=xs rows kv
    const u32x4* wm = (const u32x4*)(ws + OFF_WK);
    f32x4 acc[4];
    #pragma unroll
    for (int i = 0; i < 4; ++i) acc[i] = fz;
    for (int c0 = 0; c0 < 256; c0 += 32) {
      const int kb = (c0 >> 3) + lg;
      bf16x8 bfv = ldsfrag(xs, kvsub + lm, kb);
      #pragma unroll
      for (int i = 0; i < 4; ++i) {
        bf16x8 af = gfrag(wm, osub + i * 16 + lm, kb);
        acc[i] = MFMA16(af, bfv, acc[i], 0, 0, 0);
      }
    }
    const float* bias = (const float*)(ws + OFF_BK);
    unsigned short* ksd = (unsigned short*)(ws + OFF_KS) + (size_t)b * 256 * NC;
    const int kv = part * 32 + kvsub + lm;
    #pragma unroll
    for (int i = 0; i < 4; ++i) {
      const int ob = osub + i * 16 + lg * 4;
      const f32x4 b4 = *(const f32x4*)(bias + ob);
      u32x2 pv = { pk2(acc[i][0] + b4[0], acc[i][1] + b4[1]),
                   pk2(acc[i][2] + b4[2], acc[i][3] + b4[3]) };
      *(u32x2*)(ksd + (size_t)kv * NC + ob) = pv;
    }
  } else {
    // V: D row = kv, col = o.  A=xs rows kv, B=W rows o  -> write V^T (pi-permuted kv)
    const u32x4* wm = (const u32x4*)(ws + OFF_WV);
    f32x4 acc[4];
    #pragma unroll
    for (int j = 0; j < 4; ++j) acc[j] = fz;
    for (int c0 = 0; c0 < 256; c0 += 32) {
      const int kb = (c0 >> 3) + lg;
      bf16x8 af = ldsfrag(xs, kvsub + lm, kb);
      #pragma unroll
      for (int j = 0; j < 4; ++j) {
        bf16x8 bfv = gfrag(wm, osub + j * 16 + lm, kb);
        acc[j] = MFMA16(af, bfv, acc[j], 0, 0, 0);
      }
    }
    const float* bias = (const float*)(ws + OFF_BV);
    unsigned short* vtd = (unsigned short*)(ws + OFF_VT) + (size_t)b * 256 * 256;
    const int gp = ((lg & 1) << 1) | (lg >> 1);         // swap 4-groups 1<->2
    const int kvb = part * 32 + kvsub + gp * 4;
    #pragma unroll
    for (int j = 0; j < 4; ++j) {
      const int o = osub + j * 16 + lm;
      const float bo = bias[o];
      u32x2 pv = { pk2(acc[j][0] + bo, acc[j][1] + bo),
                   pk2(acc[j][2] + bo, acc[j][3] + bo) };
      *(u32x2*)(vtd + (size_t)o * 256 + kvb) = pv;
    }
  }
}

// ---------------- attention (32x32x16 MFMA, zero LDS, lane-local PV) ----------------
__global__ __launch_bounds__(256) void attn_kernel(unsigned char* __restrict__ ws) {
  const int bid = blockIdx.x;
  const int qt = bid & 31, h = (bid >> 5) & 3, b = bid >> 7;
  const int t = threadIdx.x, w = t >> 6, l = t & 63;
  const int ql = l & 31, hi = l >> 5;
  const int q0 = qt * 128 + w * 32;
  const u32x4* qp  = (const u32x4*)(ws + OFF_QP) + (size_t)b * NQ * 32;
  const u32x4* ksp = (const u32x4*)(ws + OFF_KS) + (size_t)b * 256 * 32;
  const u32x4* vtp = (const u32x4*)(ws + OFF_VT) + (size_t)(b * 4 + h) * 64 * 32;

  // Q frags: B-operand rows q=lane&31, k(d) = 16c + 8hi + j
  bf16x8 qf[4];
  #pragma unroll
  for (int c = 0; c < 4; ++c)
    qf[c] = __builtin_bit_cast(bf16x8, qp[(size_t)(q0 + ql) * 32 + h * 8 + 2 * c + hi]);

  f32x16 st[8];
  #pragma unroll
  for (int tt = 0; tt < 8; ++tt)
    #pragma unroll
    for (int r = 0; r < 16; ++r) st[tt][r] = 0.f;

  // S^T = K * Q^T : rows kv, cols q; lane holds col q=ql, rows (r&3)+8*(r>>2)+4*hi
  #pragma unroll
  for (int tt = 0; tt < 8; ++tt) {
    #pragma unroll
    for (int c = 0; c < 4; ++c) {
      bf16x8 kf = __builtin_bit_cast(bf16x8, ksp[(size_t)(tt * 32 + ql) * 32 + h * 8 + 2 * c + hi]);
      st[tt] = MFMA32(kf, qf[c], st[tt], 0, 0, 0);
    }
  }

  // softmax over kv for q = ql; lanes (ql,hi=0/1) hold disjoint kv halves
  f32x16 mv;
  #pragma unroll
  for (int r = 0; r < 16; ++r) {
    float m0 = fmaxf(fmaxf(st[0][r], st[1][r]), fmaxf(st[2][r], st[3][r]));
    float m1 = fmaxf(fmaxf(st[4][r], st[5][r]), fmaxf(st[6][r], st[7][r]));
    mv[r] = fmaxf(m0, m1);
  }
  float mx = mv[0];
  #pragma unroll
  for (int r = 1; r < 16; ++r) mx = fmaxf(mx, mv[r]);
  mx = fmaxf(mx, __shfl_xor(mx, 32));

  f32x16 ev;
  #pragma unroll
  for (int r = 0; r < 16; ++r) ev[r] = 0.f;
  #pragma unroll
  for (int tt = 0; tt < 8; ++tt) {
    #pragma unroll
    for (int r = 0; r < 16; ++r) {
      const float e = __expf(0.125f * (st[tt][r] - mx));
      st[tt][r] = e;
      ev[r] += e;
    }
  }
  float sum = 0.f;
  #pragma unroll
  for (int r = 0; r < 16; ++r) sum += ev[r];
  sum += __shfl_xor(sum, 32);
  const float inv = __builtin_amdgcn_rcpf(sum);

  // PV: Y^T = V^T * P.  k-permutation immunity: both operands use
  // pi(8*hi+j) = (j&3)+8*(j>>2)+4*hi, so P's B-frag is the lane's own st
  // values packed in natural order (NO cross-lane ops); V^T was stored
  // pre-permuted by kvproj to match.
  f32x16 yacc[2];
  #pragma unroll
  for (int jj = 0; jj < 2; ++jj)
    #pragma unroll
    for (int r = 0; r < 16; ++r) yacc[jj][r] = 0.f;

  #pragma unroll
  for (int step = 0; step < 16; ++step) {
    const int tt = step >> 1, bse = 8 * (step & 1);
    U16B pb;
    pb.u[0] = pk2(st[tt][bse + 0], st[tt][bse + 1]);
    pb.u[1] = pk2(st[tt][bse + 2], st[tt][bse + 3]);
    pb.u[2] = pk2(st[tt][bse + 4], st[tt][bse + 5]);
    pb.u[3] = pk2(st[tt][bse + 6], st[tt][bse + 7]);
    const bf16x8 pa = __builtin_bit_cast(bf16x8, pb.v);
    #pragma unroll
    for (int jj = 0; jj < 2; ++jj) {
      bf16x8 vf = __builtin_bit_cast(bf16x8, vtp[(size_t)(jj * 32 + ql) * 32 + step * 2 + hi]);
      yacc[jj] = MFMA32(vf, pa, yacc[jj], 0, 0, 0);
    }
  }

  // store: lane owns q = q0+ql; d = 32*jj + 8*g + 4*hi + rr (rr consecutive)
  unsigned short* yo = (unsigned short*)(ws + OFF_Y) + ((size_t)b * NQ + q0 + ql) * NC + h * 64;
  #pragma unroll
  for (int jj = 0; jj < 2; ++jj) {
    #pragma unroll
    for (int g = 0; g < 4; ++g) {
      const int d = 32 * jj + 8 * g + 4 * hi;
      u32x2 pv = { pk2(yacc[jj][4 * g + 0] * inv, yacc[jj][4 * g + 1] * inv),
                   pk2(yacc[jj][4 * g + 2] * inv, yacc[jj][4 * g + 3] * inv) };
      *(u32x2*)(yo + d) = pv;
    }
  }
}

// ---------------- dwconv + add + proj ----------------
__global__ __launch_bounds__(512) void final_kernel(float* __restrict__ out,
                                                    unsigned char* __restrict__ ws) {
  __shared__ u32x4 xs[4096];
  const int b = blockIdx.x >> 5, ntile = blockIdx.x & 31;
  const int t = threadIdx.x;
  {
    const int nl = t & 127, cq = t >> 7;
    const int n = ntile * 128 + nl;
    const int yy = n >> 6, xx = n & 63;
    const u32x4* qp = (const u32x4*)(ws + OFF_QP) + (size_t)b * NQ * 32;
    const u32x4* yv = (const u32x4*)(ws + OFF_Y) + (size_t)b * NQ * 32;
    const float* pew = (const float*)(ws + OFF_PEW);
    const float* peb = (const float*)(ws + OFF_PEB);
    #pragma unroll
    for (int it = 0; it < 8; ++it) {
      const int c0 = cq * 8 + it * 32, cb = c0 >> 3;
      float a8[8];
      #pragma unroll
      for (int j = 0; j < 8; ++j) a8[j] = peb[c0 + j];
      #pragma unroll
      for (int dy = -1; dy <= 1; ++dy) {
        #pragma unroll
        for (int dx = -1; dx <= 1; ++dx) {
          const int y2 = yy + dy, x2 = xx + dx;
          if (y2 >= 0 && y2 < 64 && x2 >= 0 && x2 < 64) {
            U16B qv; qv.v = qp[(size_t)(y2 * 64 + x2) * 32 + cb];
            const float* wr = pew + ((dy + 1) * 3 + (dx + 1)) * 256 + c0;
            #pragma unroll
            for (int j = 0; j < 8; ++j) a8[j] += bf2f(qv.s[j]) * wr[j];
          }
        }
      }
      U16B yvv; yvv.v = yv[(size_t)n * 32 + cb];
      U16B pk;
      #pragma unroll
      for (int j = 0; j < 8; ++j) pk.s[j] = f2bf(a8[j] + bf2f(yvv.s[j]));
      xs[nl * 32 + (cb ^ (nl & 7))] = pk.v;
    }
  }
  __syncthreads();
  const int l = t & 63, w = t >> 6;
  const int lm = l & 15, lg = l >> 4;
  const int osub = (w >> 1) * 64, nsub = (w & 1) * 64;
  const u32x4* wm = (const u32x4*)(ws + OFF_WP);
  const f32x4 fz = {0.f, 0.f, 0.f, 0.f};
  f32x4 acc[4][4];   // [n-tile][o-tile]: D row = n, col = o
  #pragma unroll
  for (int i = 0; i < 4; ++i)
    #pragma unroll
    for (int j = 0; j < 4; ++j) acc[i][j] = fz;
  for (int c0 = 0; c0 < 256; c0 += 32) {
    const int kb = (c0 >> 3) + lg;
    bf16x8 af[4], bfv[4];
    #pragma unroll
    for (int i = 0; i < 4; ++i) af[i] = ldsfrag(xs, nsub + i * 16 + lm, kb);
    #pragma unroll
    for (int j = 0; j < 4; ++j) bfv[j] = gfrag(wm, osub + j * 16 + lm, kb);
    #pragma unroll
    for (int i = 0; i < 4; ++i)
      #pragma unroll
      for (int j = 0; j < 4; ++j) acc[i][j] = MFMA16(af[i], bfv[j], acc[i][j], 0, 0, 0);
  }
  const float* bias = (const float*)(ws + OFF_BP);
  float* ob = out + (size_t)b * NC * NQ + ntile * 128;
  #pragma unroll
  for (int j = 0; j < 4; ++j) {
    const int o = osub + j * 16 + lm;
    const float bo = bias[o];
    #pragma unroll
    for (int i = 0; i < 4; ++i) {
      const int nb = nsub + i * 16 + lg * 4;
      f32x4 v = { acc[i][j][0] + bo, acc[i][j][1] + bo, acc[i][j][2] + bo, acc[i][j][3] + bo };
      *(f32x4*)(ob + (size_t)o * NQ + nb) = v;
    }
  }
}

extern "C" void kernel_launch(void* const* d_in, const int* in_sizes, int n_in,
                              void* d_out, int out_size, void* d_ws, size_t ws_size,
                              hipStream_t stream) {
  const float* q    = (const float*)d_in[0];
  const float* k    = (const float*)d_in[1];
  const float* v    = (const float*)d_in[2];
  const float* wq   = (const float*)d_in[3];
  const float* wqbn = (const float*)d_in[4];
  const float* wk   = (const float*)d_in[5];
  const float* wkbn = (const float*)d_in[6];
  const float* wv   = (const float*)d_in[7];
  const float* wvbn = (const float*)d_in[8];
  const float* pe   = (const float*)d_in[9];
  const float* pebn = (const float*)d_in[10];
  const float* wp   = (const float*)d_in[11];
  const float* wpbn = (const float*)d_in[12];
  unsigned char* ws = (unsigned char*)d_ws;

  prep_kernel<<<1025, 256, 0, stream>>>(wq, wqbn, wk, wkbn, wv, wvbn, wp, wpbn, pe, pebn, ws);
  qproj_kernel<<<512, 512, 0, stream>>>(q, ws);
  kvproj_kernel<<<256, 512, 0, stream>>>(k, v, ws);
  attn_kernel<<<2048, 256, 0, stream>>>(ws);
  final_kernel<<<512, 512, 0, stream>>>((float*)d_out, ws);
}

// Round 11
// 346.662 us; speedup vs baseline: 1.2228x; 1.0773x over previous
//
#include <hip/hip_runtime.h>
#include <stdint.h>

using bf16x8 = __attribute__((ext_vector_type(8))) short;
using f32x4  = __attribute__((ext_vector_type(4))) float;
using f32x16 = __attribute__((ext_vector_type(16))) float;
using u32x4  = __attribute__((ext_vector_type(4))) unsigned int;
using u32x2  = __attribute__((ext_vector_type(2))) unsigned int;

#define DEVFN static __device__ __forceinline__
#define MFMA16 __builtin_amdgcn_mfma_f32_16x16x32_bf16
#define MFMA32 __builtin_amdgcn_mfma_f32_32x32x16_bf16

#define NB 16
#define NC 256
#define NQ 4096

// workspace offsets (bytes)
#define OFF_WQ   0u
#define OFF_WK   131072u
#define OFF_WV   262144u
#define OFF_WP   393216u
#define OFF_BQ   524288u
#define OFF_BK   525312u
#define OFF_BV   526336u
#define OFF_BP   527360u
#define OFF_PEW  528384u   /* [9][256] f32 */
#define OFF_PEB  537600u   /* [256] f32   */
#define OFF_QP   1048576u  /* [B][4096][256] bf16 */
#define OFF_KS   34603008u /* [B][256][256]  bf16 */
#define OFF_VT   36700160u /* [B][256(ch)][256(kv, pi-permuted)] bf16 */
#define OFF_Y    38797312u /* [B][4096][256] bf16 */

DEVFN unsigned short f2bf(float f) {
  unsigned u = __builtin_bit_cast(unsigned, f);
  return (unsigned short)((u + 0x8000u) >> 16);
}
DEVFN float bf2f(unsigned short s) {
  return __builtin_bit_cast(float, ((unsigned)s) << 16);
}
DEVFN unsigned pk2(float a, float b) {
  return (unsigned)f2bf(a) | ((unsigned)f2bf(b) << 16);
}

union U16B { u32x4 v; unsigned u[4]; unsigned short s[8]; };

// LDS tile: rows of 32 u32x4 (256 bf16); slot index XOR-swizzled by (row&7)
DEVFN bf16x8 ldsfrag(const u32x4* xs, int row, int kb) {
  return __builtin_bit_cast(bf16x8, xs[row * 32 + (kb ^ (row & 7))]);
}
DEVFN bf16x8 gfrag(const u32x4* w, int row, int kb) {
  return __builtin_bit_cast(bf16x8, w[row * 32 + kb]);
}

// ---------------- prep: fold BN into weights ----------------
__global__ void prep_kernel(const float* __restrict__ wq, const float* __restrict__ wqbn,
                            const float* __restrict__ wk, const float* __restrict__ wkbn,
                            const float* __restrict__ wv, const float* __restrict__ wvbn,
                            const float* __restrict__ wp, const float* __restrict__ wpbn,
                            const float* __restrict__ pe, const float* __restrict__ pebn,
                            unsigned char* __restrict__ ws) {
  const int bid = blockIdx.x, c = threadIdx.x;
  if (bid < 1024) {
    const int mat = bid >> 8, o = bid & 255;
    const float* w; const float* bn; unsigned short* wd; float* bd;
    if (mat == 0)      { w = wq; bn = wqbn; wd = (unsigned short*)(ws + OFF_WQ); bd = (float*)(ws + OFF_BQ); }
    else if (mat == 1) { w = wk; bn = wkbn; wd = (unsigned short*)(ws + OFF_WK); bd = (float*)(ws + OFF_BK); }
    else if (mat == 2) { w = wv; bn = wvbn; wd = (unsigned short*)(ws + OFF_WV); bd = (float*)(ws + OFF_BV); }
    else               { w = wp; bn = wpbn; wd = (unsigned short*)(ws + OFF_WP); bd = (float*)(ws + OFF_BP); }
    const float s = bn[o] / sqrtf(bn[768 + o] + 1e-5f);
    wd[o * 256 + c] = f2bf(w[o * 256 + c] * s);
    if (c == 0) bd[o] = bn[256 + o] - bn[512 + o] * s;
  } else {
    const float s = pebn[c] / sqrtf(pebn[768 + c] + 1e-5f);
    float* pw = (float*)(ws + OFF_PEW);
    #pragma unroll
    for (int kk = 0; kk < 9; ++kk) pw[kk * 256 + c] = pe[c * 9 + kk] * s;
    ((float*)(ws + OFF_PEB))[c] = pebn[256 + c] - pebn[512 + c] * s;
  }
}

// ---------------- q projection ----------------
__global__ __launch_bounds__(512) void qproj_kernel(const float* __restrict__ q,
                                                    unsigned char* __restrict__ ws) {
  __shared__ u32x4 xs[4096];
  const int b = blockIdx.x >> 5, ntile = blockIdx.x & 31;
  const int t = threadIdx.x;
  {
    const int n4 = t & 31, cg = t >> 5;   // 4 rows, 16 channels per thread
    const float* qb = q + (size_t)b * NC * NQ + ntile * 128 + n4 * 4;
    f32x4 f4[16];
    #pragma unroll
    for (int cc = 0; cc < 16; ++cc)
      f4[cc] = *(const f32x4*)(qb + (size_t)(cg * 16 + cc) * NQ);
    #pragma unroll
    for (int rr = 0; rr < 4; ++rr) {
      const int row = n4 * 4 + rr;
      #pragma unroll
      for (int s = 0; s < 2; ++s) {
        U16B pk;
        #pragma unroll
        for (int j = 0; j < 8; ++j) pk.s[j] = f2bf(f4[s * 8 + j][rr]);
        xs[row * 32 + ((cg * 2 + s) ^ (row & 7))] = pk.v;
      }
    }
  }
  __syncthreads();
  const int l = t & 63, w = t >> 6;
  const int lm = l & 15, lg = l >> 4;
  const int nsub = (w & 1) * 64, osub = (w >> 1) * 64;
  const u32x4* wm = (const u32x4*)(ws + OFF_WQ);
  const f32x4 fz = {0.f, 0.f, 0.f, 0.f};
  f32x4 acc[4][4];   // [o-tile][n-tile]: D row = o, col = n
  #pragma unroll
  for (int i = 0; i < 4; ++i)
    #pragma unroll
    for (int j = 0; j < 4; ++j) acc[i][j] = fz;
  for (int c0 = 0; c0 < 256; c0 += 32) {
    const int kb = (c0 >> 3) + lg;
    bf16x8 af[4], bfv[4];
    #pragma unroll
    for (int i = 0; i < 4; ++i) af[i] = gfrag(wm, osub + i * 16 + lm, kb);
    #pragma unroll
    for (int j = 0; j < 4; ++j) bfv[j] = ldsfrag(xs, nsub + j * 16 + lm, kb);
    #pragma unroll
    for (int i = 0; i < 4; ++i)
      #pragma unroll
      for (int j = 0; j < 4; ++j) acc[i][j] = MFMA16(af[i], bfv[j], acc[i][j], 0, 0, 0);
  }
  const float* bias = (const float*)(ws + OFF_BQ);
  unsigned short* qp = (unsigned short*)(ws + OFF_QP) + ((size_t)b * NQ + ntile * 128) * NC;
  #pragma unroll
  for (int i = 0; i < 4; ++i) {
    const int ob = osub + i * 16 + lg * 4;
    const f32x4 b4 = *(const f32x4*)(bias + ob);
    #pragma unroll
    for (int j = 0; j < 4; ++j) {
      const int n = nsub + j * 16 + lm;
      u32x2 pv = { pk2(acc[i][j][0] + b4[0], acc[i][j][1] + b4[1]),
                   pk2(acc[i][j][2] + b4[2], acc[i][j][3] + b4[3]) };
      *(u32x2*)(qp + (size_t)n * NC + ob) = pv;
    }
  }
}

// ---------------- pooled K/V projection ----------------
// 8 waves: osub = (w>>1)*64 (0..192), kvsub = (w&1)*16
// V^T is stored with each 16-kv block's 4-groups permuted g->g' (swap groups 1,2)
// so attn's linear reads deliver k-slots in the lane-local pi order.
__global__ __launch_bounds__(512) void kvproj_kernel(const float* __restrict__ kin,
                                                     const float* __restrict__ vin,
                                                     unsigned char* __restrict__ ws) {
  __shared__ u32x4 xs[1024];  // 32 rows x 256 ch bf16, swizzled
  const int bid = blockIdx.x;
  const int b = bid >> 4, which = (bid >> 3) & 1, part = bid & 7;
  const int t = threadIdx.x;
  {
    const int nl = t & 31, cq = t >> 5;  // row, 16 ch per thread
    const int kv = part * 32 + nl;
    const int yy = kv >> 4, xx = kv & 15;
    const float* src = (which ? vin : kin) + (size_t)b * NC * 1024 + (2 * yy) * 32 + 2 * xx;
    #pragma unroll
    for (int s = 0; s < 2; ++s) {
      const int c0 = cq * 16 + s * 8;
      U16B pk;
      #pragma unroll
      for (int j = 0; j < 8; ++j) {
        const float* p = src + (size_t)(c0 + j) * 1024;
        const float2 p01 = *(const float2*)p;
        const float2 p23 = *(const float2*)(p + 32);
        pk.s[j] = f2bf((p01.x + p01.y + p23.x + p23.y) * 0.25f);
      }
      xs[nl * 32 + ((c0 >> 3) ^ (nl & 7))] = pk.v;
    }
  }
  __syncthreads();
  const int l = t & 63, w = t >> 6;
  const int lm = l & 15, lg = l >> 4;
  const int osub = (w >> 1) * 64;     // 0..192
  const int kvsub = (w & 1) * 16;     // 0 or 16
  const f32x4 fz = {0.f, 0.f, 0.f, 0.f};
  if (which == 0) {
    // K: D row = o, col = kv.  A=W rows o, B=xs rows kv
    const u32x4* wm = (const u32x4*)(ws + OFF_WK);
    f32x4 acc[4];
    #pragma unroll
    for (int i = 0; i < 4; ++i) acc[i] = fz;
    for (int c0 = 0; c0 < 256; c0 += 32) {
      const int kb = (c0 >> 3) + lg;
      bf16x8 bfv = ldsfrag(xs, kvsub + lm, kb);
      #pragma unroll
      for (int i = 0; i < 4; ++i) {
        bf16x8 af = gfrag(wm, osub + i * 16 + lm, kb);
        acc[i] = MFMA16(af, bfv, acc[i], 0, 0, 0);
      }
    }
    const float* bias = (const float*)(ws + OFF_BK);
    unsigned short* ksd = (unsigned short*)(ws + OFF_KS) + (size_t)b * 256 * NC;
    const int kv = part * 32 + kvsub + lm;
    #pragma unroll
    for (int i = 0; i < 4; ++i) {
      const int ob = osub + i * 16 + lg * 4;
      const f32x4 b4 = *(const f32x4*)(bias + ob);
      u32x2 pv = { pk2(acc[i][0] + b4[0], acc[i][1] + b4[1]),
                   pk2(acc[i][2] + b4[2], acc[i][3] + b4[3]) };
      *(u32x2*)(ksd + (size_t)kv * NC + ob) = pv;
    }
  } else {
    // V: D row = kv, col = o.  A=xs rows kv, B=W rows o  -> write V^T (pi-permuted kv)
    const u32x4* wm = (const u32x4*)(ws + OFF_WV);
    f32x4 acc[4];
    #pragma unroll
    for (int j = 0; j < 4; ++j) acc[j] = fz;
    for (int c0 = 0; c0 < 256; c0 += 32) {
      const int kb = (c0 >> 3) + lg;
      bf16x8 af = ldsfrag(xs, kvsub + lm, kb);
      #pragma unroll
      for (int j = 0; j < 4; ++j) {
        bf16x8 bfv = gfrag(wm, osub + j * 16 + lm, kb);
        acc[j] = MFMA16(af, bfv, acc[j], 0, 0, 0);
      }
    }
    const float* bias = (const float*)(ws + OFF_BV);
    unsigned short* vtd = (unsigned short*)(ws + OFF_VT) + (size_t)b * 256 * 256;
    const int gp = ((lg & 1) << 1) | (lg >> 1);         // swap 4-groups 1<->2
    const int kvb = part * 32 + kvsub + gp * 4;
    #pragma unroll
    for (int j = 0; j < 4; ++j) {
      const int o = osub + j * 16 + lm;
      const float bo = bias[o];
      u32x2 pv = { pk2(acc[j][0] + bo, acc[j][1] + bo),
                   pk2(acc[j][2] + bo, acc[j][3] + bo) };
      *(u32x2*)(vtd + (size_t)o * 256 + kvb) = pv;
    }
  }
}

// ---------------- attention (32x32x16 MFMA, zero LDS, lane-local PV) ----------------
__global__ __launch_bounds__(256) void attn_kernel(unsigned char* __restrict__ ws) {
  const int bid = blockIdx.x;
  const int qt = bid & 31, h = (bid >> 5) & 3, b = bid >> 7;
  const int t = threadIdx.x, w = t >> 6, l = t & 63;
  const int ql = l & 31, hi = l >> 5;
  const int q0 = qt * 128 + w * 32;
  const u32x4* qp  = (const u32x4*)(ws + OFF_QP) + (size_t)b * NQ * 32;
  const u32x4* ksp = (const u32x4*)(ws + OFF_KS) + (size_t)b * 256 * 32;
  const u32x4* vtp = (const u32x4*)(ws + OFF_VT) + (size_t)(b * 4 + h) * 64 * 32;

  // Q frags: B-operand rows q=lane&31, k(d) = 16c + 8hi + j
  bf16x8 qf[4];
  #pragma unroll
  for (int c = 0; c < 4; ++c)
    qf[c] = __builtin_bit_cast(bf16x8, qp[(size_t)(q0 + ql) * 32 + h * 8 + 2 * c + hi]);

  f32x16 st[8];
  #pragma unroll
  for (int tt = 0; tt < 8; ++tt)
    #pragma unroll
    for (int r = 0; r < 16; ++r) st[tt][r] = 0.f;

  // S^T = K * Q^T : rows kv, cols q; lane holds col q=ql, rows (r&3)+8*(r>>2)+4*hi
  #pragma unroll
  for (int tt = 0; tt < 8; ++tt) {
    #pragma unroll
    for (int c = 0; c < 4; ++c) {
      bf16x8 kf = __builtin_bit_cast(bf16x8, ksp[(size_t)(tt * 32 + ql) * 32 + h * 8 + 2 * c + hi]);
      st[tt] = MFMA32(kf, qf[c], st[tt], 0, 0, 0);
    }
  }

  // softmax over kv for q = ql; lanes (ql,hi=0/1) hold disjoint kv halves
  f32x16 mv;
  #pragma unroll
  for (int r = 0; r < 16; ++r) {
    float m0 = fmaxf(fmaxf(st[0][r], st[1][r]), fmaxf(st[2][r], st[3][r]));
    float m1 = fmaxf(fmaxf(st[4][r], st[5][r]), fmaxf(st[6][r], st[7][r]));
    mv[r] = fmaxf(m0, m1);
  }
  float mx = mv[0];
  #pragma unroll
  for (int r = 1; r < 16; ++r) mx = fmaxf(mx, mv[r]);
  mx = fmaxf(mx, __shfl_xor(mx, 32));

  f32x16 ev;
  #pragma unroll
  for (int r = 0; r < 16; ++r) ev[r] = 0.f;
  #pragma unroll
  for (int tt = 0; tt < 8; ++tt) {
    #pragma unroll
    for (int r = 0; r < 16; ++r) {
      const float e = __expf(0.125f * (st[tt][r] - mx));
      st[tt][r] = e;
      ev[r] += e;
    }
  }
  float sum = 0.f;
  #pragma unroll
  for (int r = 0; r < 16; ++r) sum += ev[r];
  sum += __shfl_xor(sum, 32);
  const float inv = __builtin_amdgcn_rcpf(sum);

  // PV: Y^T = V^T * P.  k-permutation immunity: both operands use
  // pi(8*hi+j) = (j&3)+8*(j>>2)+4*hi, so P's B-frag is the lane's own st
  // values packed in natural order (NO cross-lane ops); V^T was stored
  // pre-permuted by kvproj to match.
  f32x16 yacc[2];
  #pragma unroll
  for (int jj = 0; jj < 2; ++jj)
    #pragma unroll
    for (int r = 0; r < 16; ++r) yacc[jj][r] = 0.f;

  #pragma unroll
  for (int step = 0; step < 16; ++step) {
    const int tt = step >> 1, bse = 8 * (step & 1);
    U16B pb;
    pb.u[0] = pk2(st[tt][bse + 0], st[tt][bse + 1]);
    pb.u[1] = pk2(st[tt][bse + 2], st[tt][bse + 3]);
    pb.u[2] = pk2(st[tt][bse + 4], st[tt][bse + 5]);
    pb.u[3] = pk2(st[tt][bse + 6], st[tt][bse + 7]);
    const bf16x8 pa = __builtin_bit_cast(bf16x8, pb.v);
    #pragma unroll
    for (int jj = 0; jj < 2; ++jj) {
      bf16x8 vf = __builtin_bit_cast(bf16x8, vtp[(size_t)(jj * 32 + ql) * 32 + step * 2 + hi]);
      yacc[jj] = MFMA32(vf, pa, yacc[jj], 0, 0, 0);
    }
  }

  // store: lane owns q = q0+ql; d = 32*jj + 8*g + 4*hi + rr (rr consecutive)
  unsigned short* yo = (unsigned short*)(ws + OFF_Y) + ((size_t)b * NQ + q0 + ql) * NC + h * 64;
  #pragma unroll
  for (int jj = 0; jj < 2; ++jj) {
    #pragma unroll
    for (int g = 0; g < 4; ++g) {
      const int d = 32 * jj + 8 * g + 4 * hi;
      u32x2 pv = { pk2(yacc[jj][4 * g + 0] * inv, yacc[jj][4 * g + 1] * inv),
                   pk2(yacc[jj][4 * g + 2] * inv, yacc[jj][4 * g + 3] * inv) };
      *(u32x2*)(yo + d) = pv;
    }
  }
}

// ---------------- dwconv + add + proj ----------------
// Staging maps lane -> channel-group (cg = t&31): every tap load is a
// contiguous 512B segment per 32 lanes (was 512B-stride scatter), and the
// 3x3 bounds branch is uniform per 32-lane group.
__global__ __launch_bounds__(512) void final_kernel(float* __restrict__ out,
                                                    unsigned char* __restrict__ ws) {
  __shared__ u32x4 xs[4096];
  const int b = blockIdx.x >> 5, ntile = blockIdx.x & 31;
  const int t = threadIdx.x;
  {
    const int cg = t & 31, tl = t >> 5;   // channel u32x4 index, token sub-index
    const u32x4* qp = (const u32x4*)(ws + OFF_QP) + (size_t)b * NQ * 32;
    const u32x4* yv = (const u32x4*)(ws + OFF_Y) + (size_t)b * NQ * 32;
    const float* pew = (const float*)(ws + OFF_PEW);
    const float* peb = (const float*)(ws + OFF_PEB);
    float bb[8];
    #pragma unroll
    for (int j = 0; j < 8; ++j) bb[j] = peb[cg * 8 + j];
    #pragma unroll
    for (int it = 0; it < 8; ++it) {
      const int nl = it * 16 + tl;
      const int n = ntile * 128 + nl;
      const int yy = n >> 6, xx = n & 63;
      float a8[8];
      #pragma unroll
      for (int j = 0; j < 8; ++j) a8[j] = bb[j];
      #pragma unroll
      for (int dy = -1; dy <= 1; ++dy) {
        #pragma unroll
        for (int dx = -1; dx <= 1; ++dx) {
          const int y2 = yy + dy, x2 = xx + dx;
          if (y2 >= 0 && y2 < 64 && x2 >= 0 && x2 < 64) {
            U16B qv; qv.v = qp[(size_t)(y2 * 64 + x2) * 32 + cg];
            const float* wr = pew + ((dy + 1) * 3 + (dx + 1)) * 256 + cg * 8;
            #pragma unroll
            for (int j = 0; j < 8; ++j) a8[j] += bf2f(qv.s[j]) * wr[j];
          }
        }
      }
      U16B yvv; yvv.v = yv[(size_t)n * 32 + cg];
      U16B pk;
      #pragma unroll
      for (int j = 0; j < 8; ++j) pk.s[j] = f2bf(a8[j] + bf2f(yvv.s[j]));
      xs[nl * 32 + (cg ^ (nl & 7))] = pk.v;
    }
  }
  __syncthreads();
  const int l = t & 63, w = t >> 6;
  const int lm = l & 15, lg = l >> 4;
  const int osub = (w >> 1) * 64, nsub = (w & 1) * 64;
  const u32x4* wm = (const u32x4*)(ws + OFF_WP);
  const f32x4 fz = {0.f, 0.f, 0.f, 0.f};
  f32x4 acc[4][4];   // [n-tile][o-tile]: D row = n, col = o
  #pragma unroll
  for (int i = 0; i < 4; ++i)
    #pragma unroll
    for (int j = 0; j < 4; ++j) acc[i][j] = fz;
  for (int c0 = 0; c0 < 256; c0 += 32) {
    const int kb = (c0 >> 3) + lg;
    bf16x8 af[4], bfv[4];
    #pragma unroll
    for (int i = 0; i < 4; ++i) af[i] = ldsfrag(xs, nsub + i * 16 + lm, kb);
    #pragma unroll
    for (int j = 0; j < 4; ++j) bfv[j] = gfrag(wm, osub + j * 16 + lm, kb);
    #pragma unroll
    for (int i = 0; i < 4; ++i)
      #pragma unroll
      for (int j = 0; j < 4; ++j) acc[i][j] = MFMA16(af[i], bfv[j], acc[i][j], 0, 0, 0);
  }
  const float* bias = (const float*)(ws + OFF_BP);
  float* ob = out + (size_t)b * NC * NQ + ntile * 128;
  #pragma unroll
  for (int j = 0; j < 4; ++j) {
    const int o = osub + j * 16 + lm;
    const float bo = bias[o];
    #pragma unroll
    for (int i = 0; i < 4; ++i) {
      const int nb = nsub + i * 16 + lg * 4;
      f32x4 v = { acc[i][j][0] + bo, acc[i][j][1] + bo, acc[i][j][2] + bo, acc[i][j][3] + bo };
      *(f32x4*)(ob + (size_t)o * NQ + nb) = v;
    }
  }
}

extern "C" void kernel_launch(void* const* d_in, const int* in_sizes, int n_in,
                              void* d_out, int out_size, void* d_ws, size_t ws_size,
                              hipStream_t stream) {
  const float* q    = (const float*)d_in[0];
  const float* k    = (const float*)d_in[1];
  const float* v    = (const float*)d_in[2];
  const float* wq   = (const float*)d_in[3];
  const float* wqbn = (const float*)d_in[4];
  const float* wk   = (const float*)d_in[5];
  const float* wkbn = (const float*)d_in[6];
  const float* wv   = (const float*)d_in[7];
  const float* wvbn = (const float*)d_in[8];
  const float* pe   = (const float*)d_in[9];
  const float* pebn = (const float*)d_in[10];
  const float* wp   = (const float*)d_in[11];
  const float* wpbn = (const float*)d_in[12];
  unsigned char* ws = (unsigned char*)d_ws;

  prep_kernel<<<1025, 256, 0, stream>>>(wq, wqbn, wk, wkbn, wv, wvbn, wp, wpbn, pe, pebn, ws);
  qproj_kernel<<<512, 512, 0, stream>>>(q, ws);
  kvproj_kernel<<<256, 512, 0, stream>>>(k, v, ws);
  attn_kernel<<<2048, 256, 0, stream>>>(ws);
  final_kernel<<<512, 512, 0, stream>>>((float*)d_out, ws);
}